// Round 12
// baseline (211.109 us; speedup 1.0000x reference)
//
#include <hip/hip_runtime.h>
#include <math.h>

typedef __bf16 bf16x8 __attribute__((ext_vector_type(8)));
typedef __bf16 bf16x4 __attribute__((ext_vector_type(4)));
typedef float  f32x4  __attribute__((ext_vector_type(4)));

namespace {
constexpr int L_ = 512, D_ = 512, NF = 11;
constexpr long WE = (long)L_ * L_;   // 262144 elems, one 512x512 plane
constexpr long NE = 8 * WE;          // 2097152 elems, B*L*D
constexpr long CPL = 512L * 1024;    // concatenated plane (512 rows x 1024)
constexpr float NEGV = -1.0e9f;
constexpr float INV_TEMP = 0.044194173824159216f; // 1/sqrt(512)
}

typedef __attribute__((address_space(1))) void gv_t;
typedef __attribute__((address_space(3))) void lv_t;

__device__ __forceinline__ void async_cp16(const void* g, void* l) {
  __builtin_amdgcn_global_load_lds((gv_t*)g, (lv_t*)l, 16, 0, 0);
}

__device__ __forceinline__ bf16x8 cvt2(float4 a0, float4 a1) {
  bf16x8 f;
  f[0] = (__bf16)a0.x; f[1] = (__bf16)a0.y; f[2] = (__bf16)a0.z; f[3] = (__bf16)a0.w;
  f[4] = (__bf16)a1.x; f[5] = (__bf16)a1.y; f[6] = (__bf16)a1.z; f[7] = (__bf16)a1.w;
  return f;
}

// ======== 128x128 NT core: 4 waves x (64x64, 4x4 acc), BK=64 as two 32-panels, ========
// VGPR-prefetch staging; fp32 operands converted in-register (same RNE points as
// a pre-conversion pass). Thread t stages row t>>1, panel t&1 (32 cols) of A and B.
template<bool AF32, bool BF32>
__device__ __forceinline__ void core_big(const void* Av, const void* Bv,
                                         int K, int m0, int n0,
                                         __bf16* sA, __bf16* sB, f32x4 (&acc)[4][4])
{
  const int tid = threadIdx.x;
  const int wave = tid >> 6, lane = tid & 63;
  const int quad = lane >> 4, l16 = lane & 15;
  const int wm = (wave >> 1) * 64, wn = (wave & 1) * 64;
  const int srow = tid >> 1, spanel = tid & 1;
  const float*  gAf = (const float*)Av  + (long)(m0 + srow) * K + spanel * 32;
  const __bf16* gAb = (const __bf16*)Av + (long)(m0 + srow) * K + spanel * 32;
  const float*  gBf = (const float*)Bv  + (long)(n0 + srow) * K + spanel * 32;
  const __bf16* gBb = (const __bf16*)Bv + (long)(n0 + srow) * K + spanel * 32;
  __bf16* dA = sA + spanel * 4096 + srow * 32;   // panels: [2][128][32]
  __bf16* dB = sB + spanel * 4096 + srow * 32;

  float4 fa[8], fb[8];
  bf16x8 ba[4], bb[4];

  // tile-0 prefetch
  if (AF32) {
    #pragma unroll
    for (int i = 0; i < 8; ++i) fa[i] = *(const float4*)(gAf + i * 4);
  } else {
    #pragma unroll
    for (int i = 0; i < 4; ++i) ba[i] = *(const bf16x8*)(gAb + i * 8);
  }
  if (BF32) {
    #pragma unroll
    for (int i = 0; i < 8; ++i) fb[i] = *(const float4*)(gBf + i * 4);
  } else {
    #pragma unroll
    for (int i = 0; i < 4; ++i) bb[i] = *(const bf16x8*)(gBb + i * 8);
  }

  for (int k0 = 0; k0 < K; k0 += 64) {
    __syncthreads();                 // all waves done reading previous LDS tile
    #pragma unroll
    for (int j = 0; j < 4; ++j) {
      bf16x8 wa = AF32 ? cvt2(fa[2 * j], fa[2 * j + 1]) : ba[j];
      *(bf16x8*)(dA + j * 8) = wa;
    }
    #pragma unroll
    for (int j = 0; j < 4; ++j) {
      bf16x8 wb = BF32 ? cvt2(fb[2 * j], fb[2 * j + 1]) : bb[j];
      *(bf16x8*)(dB + j * 8) = wb;
    }
    __syncthreads();                 // writes visible
    if (k0 + 64 < K) {               // issue next tile's loads; waits land next iter
      const int kn = k0 + 64;
      if (AF32) {
        #pragma unroll
        for (int i = 0; i < 8; ++i) fa[i] = *(const float4*)(gAf + kn + i * 4);
      } else {
        #pragma unroll
        for (int i = 0; i < 4; ++i) ba[i] = *(const bf16x8*)(gAb + kn + i * 8);
      }
      if (BF32) {
        #pragma unroll
        for (int i = 0; i < 8; ++i) fb[i] = *(const float4*)(gBf + kn + i * 4);
      } else {
        #pragma unroll
        for (int i = 0; i < 4; ++i) bb[i] = *(const bf16x8*)(gBb + kn + i * 8);
      }
    }
    #pragma unroll
    for (int p = 0; p < 2; ++p) {
      bf16x8 af[4], bfr[4];
      #pragma unroll
      for (int i = 0; i < 4; ++i)
        af[i]  = *(const bf16x8*)(sA + p * 4096 + (wm + i * 16 + l16) * 32 + quad * 8);
      #pragma unroll
      for (int j = 0; j < 4; ++j)
        bfr[j] = *(const bf16x8*)(sB + p * 4096 + (wn + j * 16 + l16) * 32 + quad * 8);
      #pragma unroll
      for (int i = 0; i < 4; ++i)
        #pragma unroll
        for (int j = 0; j < 4; ++j)
          acc[i][j] = __builtin_amdgcn_mfma_f32_16x16x32_bf16(af[i], bfr[j], acc[i][j], 0, 0, 0);
    }
  }
}

// ======== 64x64 NT core, BK=64 panels, bf16 operands (scores) ========
__device__ __forceinline__ void core64(const __bf16* __restrict__ A, const __bf16* __restrict__ B,
                                       int K, int m0, int n0,
                                       __bf16* sA, __bf16* sB, f32x4 (&acc)[2][2])
{
  const int tid = threadIdx.x;
  const int wave = tid >> 6, lane = tid & 63;
  const int srow = tid >> 2, scol = (tid & 3) * 8;
  const int quad = lane >> 4, l16 = lane & 15;
  const int wm = (wave >> 1) * 32, wn = (wave & 1) * 32;
  const __bf16* gA = A + (long)(m0 + srow) * K + scol;
  const __bf16* gB = B + (long)(n0 + srow) * K + scol;
  __bf16* dA = sA + srow * 32 + scol;
  __bf16* dB = sB + srow * 32 + scol;

  bf16x8 ra[2], rb[2];
  ra[0] = *(const bf16x8*)(gA);
  ra[1] = *(const bf16x8*)(gA + 32);
  rb[0] = *(const bf16x8*)(gB);
  rb[1] = *(const bf16x8*)(gB + 32);

  for (int k0 = 0; k0 < K; k0 += 64) {
    __syncthreads();
    *(bf16x8*)(dA)        = ra[0];
    *(bf16x8*)(dA + 2048) = ra[1];
    *(bf16x8*)(dB)        = rb[0];
    *(bf16x8*)(dB + 2048) = rb[1];
    __syncthreads();
    if (k0 + 64 < K) {
      const int kn = k0 + 64;
      ra[0] = *(const bf16x8*)(gA + kn);
      ra[1] = *(const bf16x8*)(gA + kn + 32);
      rb[0] = *(const bf16x8*)(gB + kn);
      rb[1] = *(const bf16x8*)(gB + kn + 32);
    }
    #pragma unroll
    for (int p = 0; p < 2; ++p) {
      bf16x8 af[2], bfr[2];
      #pragma unroll
      for (int i = 0; i < 2; ++i)
        af[i]  = *(const bf16x8*)(sA + p * 2048 + (wm + i * 16 + l16) * 32 + quad * 8);
      #pragma unroll
      for (int j = 0; j < 2; ++j)
        bfr[j] = *(const bf16x8*)(sB + p * 2048 + (wn + j * 16 + l16) * 32 + quad * 8);
      #pragma unroll
      for (int i = 0; i < 2; ++i)
        #pragma unroll
        for (int j = 0; j < 2; ++j)
          acc[i][j] = __builtin_amdgcn_mfma_f32_16x16x32_bf16(af[i], bfr[j], acc[i][j], 0, 0, 0);
    }
  }
}

// ======== projfeat: flat grid. fid<640: 128x128 GEMM (XCD-swizzled); fid>=640: feat ========
// z: 0=qp->qcat[:,:512] 1=kp->kcat[:,:512] 2=qfT 3=kfT 4=vp
__global__ __launch_bounds__(256)
void projfeat_kernel(const float* __restrict__ q, const float* __restrict__ k,
                     const float* __restrict__ v,
                     const float* __restrict__ Wq, const float* __restrict__ Wk,
                     const float* __restrict__ Wqf, const float* __restrict__ Wkf,
                     const float* __restrict__ Wv,
                     const float* __restrict__ x, const float* __restrict__ imp,
                     const int* __restrict__ lens,
                     __bf16* __restrict__ qcat, __bf16* __restrict__ kcat,
                     __bf16* __restrict__ qfkfT, __bf16* __restrict__ vpb,
                     __bf16* __restrict__ featb)
{
  __shared__ __align__(16) char smem[32768]; // GEMM: sA 16K + sB 16K; feat: 22.5K
  const int fid = blockIdx.x;
  const int tid = threadIdx.x;
  const int wave = tid >> 6, lane = tid & 63;

  if (fid < 640) {
    const int xcd = fid & 7, g = fid >> 3;       // g in [0,80)
    const int n = g & 3, mh = (g >> 2) & 3, z = g >> 4;
    const int m0 = (mh * 8 + xcd) * 128;         // m-tile in [0,32)
    const int n0 = n * 128;
    __bf16* sA = (__bf16*)smem;
    __bf16* sB = sA + 2 * 128 * 32;
    const float* As[5] = {q, k, q, k, v};
    const float* Bs[5] = {Wq, Wk, Wqf, Wkf, Wv};
    f32x4 acc[4][4];
    #pragma unroll
    for (int i = 0; i < 4; ++i)
      #pragma unroll
      for (int j = 0; j < 4; ++j) acc[i][j] = 0.0f;
    core_big<true, true>(As[z], Bs[z], 512, m0, n0, sA, sB, acc);

    const int quad = lane >> 4, l16 = lane & 15;
    const int wm = (wave >> 1) * 64, wn = (wave & 1) * 64;
    #pragma unroll
    for (int i = 0; i < 4; ++i) {
      const int mb = m0 + wm + i * 16 + quad * 4;
      #pragma unroll
      for (int j = 0; j < 4; ++j) {
        const int nn = n0 + wn + j * 16 + l16;
        f32x4 c = acc[i][j];
        if (z < 2) {
          __bf16* C = (z == 0) ? qcat : kcat;
          #pragma unroll
          for (int r2 = 0; r2 < 4; ++r2)
            C[(long)(mb + r2) * 1024 + nn] = (__bf16)c[r2];
        } else if (z == 4) {
          #pragma unroll
          for (int r2 = 0; r2 < 4; ++r2)
            vpb[(long)(mb + r2) * 512 + nn] = (__bf16)c[r2];
        } else {
          __bf16* T = qfkfT + (long)(z - 2) * NE;
          const long bb = (long)(mb >> 9) << 18;
          const int l = mb & 511;
          bf16x4 pk;
          pk[0] = (__bf16)c[0]; pk[1] = (__bf16)c[1];
          pk[2] = (__bf16)c[2]; pk[3] = (__bf16)c[3];
          *(bf16x4*)(T + bb + (long)nn * 512 + l) = pk;
        }
      }
    }
  } else {
    const int flat = fid - 640;                  // 0..127
    float* xfs = (float*)smem;                   // 22.5 KB
    const int b = flat >> 4;
    const int i0 = (flat & 15) * 32;
    for (int idx = tid; idx < L_ * NF; idx += 256) {
      int j = idx / NF, f = idx - j * NF;
      xfs[idx] = x[((long)b * L_ + j) * D_ + f];
    }
    float im[NF];
    #pragma unroll
    for (int f = 0; f < NF; ++f) im[f] = imp[f];
    const int len = lens[b];
    __syncthreads();
    for (int r = 0; r < 8; ++r) {
      const int i = i0 + wave * 8 + r;
      float xi[NF];
      #pragma unroll
      for (int f = 0; f < NF; ++f) xi[f] = xfs[i * NF + f];
      float l[8];
      float m = -INFINITY;
      #pragma unroll
      for (int t = 0; t < 8; ++t) {
        int j = lane + t * 64;
        float s = 0.f;
        #pragma unroll
        for (int f = 0; f < NF; ++f) s = fmaf(fabsf(xi[f] - xfs[j * NF + f]), im[f], s);
        s = (j < len) ? s : NEGV;
        l[t] = s;
        m = fmaxf(m, s);
      }
      #pragma unroll
      for (int o = 32; o >= 1; o >>= 1) m = fmaxf(m, __shfl_xor(m, o));
      float ssum = 0.f;
      #pragma unroll
      for (int t = 0; t < 8; ++t) { l[t] = expf(l[t] - m); ssum += l[t]; }
      #pragma unroll
      for (int o = 32; o >= 1; o >>= 1) ssum += __shfl_xor(ssum, o);
      float inv = 1.0f / ssum;
      #pragma unroll
      for (int t = 0; t < 8; ++t)
        featb[((long)b * L_ + i) * L_ + lane + t * 64] = (__bf16)(l[t] * inv);
    }
  }
}

// mega2 (128x128 core): z 0..7 qf2->qcat[:,512:], 8..15 kf2->kcat[:,512:], 16..23 vp2T=NT(Wfc,vp[b])
__global__ __launch_bounds__(256)
void mega2_kernel(const __bf16* __restrict__ featb, const __bf16* __restrict__ qfkfT,
                  const float* __restrict__ Wfc, const __bf16* __restrict__ vpb,
                  __bf16* __restrict__ qcat, __bf16* __restrict__ kcat,
                  __bf16* __restrict__ vp2T)
{
  __shared__ __align__(16) __bf16 sA[2 * 128 * 32];
  __shared__ __align__(16) __bf16 sB[2 * 128 * 32];
  const int z = blockIdx.z;
  const int m0 = blockIdx.y * 128, n0 = blockIdx.x * 128;
  f32x4 acc[4][4];
  #pragma unroll
  for (int i = 0; i < 4; ++i)
    #pragma unroll
    for (int j = 0; j < 4; ++j) acc[i][j] = 0.0f;

  __bf16* C;
  int ldc;
  if (z < 16) {
    const int b = z & 7, s = z >> 3;
    const __bf16* A = featb + (long)b * WE;
    const __bf16* B = qfkfT + (long)s * NE + (long)b * WE;
    C = (s ? kcat : qcat) + (long)b * CPL + 512;
    ldc = 1024;
    core_big<false, false>(A, B, 512, m0, n0, sA, sB, acc);
  } else {
    const int b = z - 16;
    const __bf16* B = vpb + (long)b * WE;
    C = vp2T + (long)b * WE;
    ldc = 512;
    core_big<true, false>(Wfc, B, 512, m0, n0, sA, sB, acc);
  }

  const int wave = threadIdx.x >> 6, lane = threadIdx.x & 63;
  const int quad = lane >> 4, l16 = lane & 15;
  const int wm = (wave >> 1) * 64, wn = (wave & 1) * 64;
  #pragma unroll
  for (int i = 0; i < 4; ++i) {
    const int mb = m0 + wm + i * 16 + quad * 4;
    #pragma unroll
    for (int j = 0; j < 4; ++j) {
      const int nn = n0 + wn + j * 16 + l16;
      f32x4 c = acc[i][j];
      #pragma unroll
      for (int r2 = 0; r2 < 4; ++r2)
        C[(long)(mb + r2) * ldc + nn] = (__bf16)c[r2];
    }
  }
}

// scores: attn = tanh(mask(./temp)), K=1024, 64x64 tiles; writes fp32 (out1) + bf16 (for av2)
__global__ __launch_bounds__(256)
void scores_kernel(const __bf16* __restrict__ qcat, const __bf16* __restrict__ kcat,
                   const int* __restrict__ lens, float* __restrict__ attnf,
                   __bf16* __restrict__ attnb)
{
  __shared__ __align__(16) __bf16 sA[2 * 64 * 32];
  __shared__ __align__(16) __bf16 sB[2 * 64 * 32];
  const int b = blockIdx.z;
  const int len = lens[b];
  const int m0 = blockIdx.y * 64, n0 = blockIdx.x * 64;
  f32x4 acc[2][2];
  #pragma unroll
  for (int i = 0; i < 2; ++i)
    #pragma unroll
    for (int j = 0; j < 2; ++j) acc[i][j] = 0.0f;
  core64(qcat + (long)b * CPL, kcat + (long)b * CPL, 1024, m0, n0, sA, sB, acc);

  const long off = (long)b * WE;
  const int wave = threadIdx.x >> 6, lane = threadIdx.x & 63;
  const int quad = lane >> 4, l16 = lane & 15;
  const int wm = (wave >> 1) * 32, wn = (wave & 1) * 32;
  #pragma unroll
  for (int i = 0; i < 2; ++i) {
    const int mb = m0 + wm + i * 16 + quad * 4;
    #pragma unroll
    for (int j = 0; j < 2; ++j) {
      const int nn = n0 + wn + j * 16 + l16;
      f32x4 c = acc[i][j];
      #pragma unroll
      for (int r2 = 0; r2 < 4; ++r2) {
        float vv = c[r2] * INV_TEMP;
        vv = (nn < len) ? tanhf(vv) : 0.0f;
        attnf[off + (long)(mb + r2) * 512 + nn] = vv;
        attnb[off + (long)(mb + r2) * 512 + nn] = (__bf16)vv;
      }
    }
  }
}

// ======== av2ln: out = LN(attn@vp2 + q); block = 16 rows x full 512 cols ========
__global__ __launch_bounds__(256)
void av2ln_kernel(const __bf16* __restrict__ attnb, const __bf16* __restrict__ vp2T,
                  const float* __restrict__ q, const float* __restrict__ gamma,
                  const float* __restrict__ beta, float* __restrict__ outp)
{
  __shared__ __align__(16) __bf16 sA[16 * 32];     // 1 KB
  __shared__ __align__(16) __bf16 sB[512 * 32];    // 32 KB
  __shared__ float lnbuf[4][16][2];
  __shared__ float lnmv[16][2];
  const int b = blockIdx.z;
  const int m0 = blockIdx.x * 16;
  const int tid = threadIdx.x;
  const int wave = tid >> 6, lane = tid & 63;
  const int quad = lane >> 4, l16 = lane & 15;
  const long aoff = (long)b * WE;

  f32x4 acc[8];
  #pragma unroll
  for (int j = 0; j < 8; ++j) acc[j] = 0.0f;

  for (int k0 = 0; k0 < 512; k0 += 32) {
    __syncthreads();
    if (wave == 0) {
      const int ar = lane >> 2, ac = (lane & 3) * 8;
      async_cp16(attnb + aoff + (long)(m0 + ar) * 512 + k0 + ac, (char*)sA + lane * 16);
    }
    #pragma unroll
    for (int it = 0; it < 8; ++it) {
      const int chunk = it * 4 + wave;
      const int d = chunk * 16 + (lane >> 2), c = (lane & 3) * 8;
      async_cp16(vp2T + aoff + (long)d * 512 + k0 + c, (char*)sB + chunk * 1024 + lane * 16);
    }
    __syncthreads();
    bf16x8 af = *(const bf16x8*)(sA + l16 * 32 + quad * 8);
    #pragma unroll
    for (int j = 0; j < 8; ++j) {
      bf16x8 bfr = *(const bf16x8*)(sB + (wave * 128 + j * 16 + l16) * 32 + quad * 8);
      acc[j] = __builtin_amdgcn_mfma_f32_16x16x32_bf16(af, bfr, acc[j], 0, 0, 0);
    }
  }

  float uval[8][4];
  float s[4] = {0.f, 0.f, 0.f, 0.f}, ss[4] = {0.f, 0.f, 0.f, 0.f};
  #pragma unroll
  for (int r = 0; r < 4; ++r) {
    const long row = (long)b * 512 + m0 + quad * 4 + r;
    #pragma unroll
    for (int j = 0; j < 8; ++j) {
      const int col = wave * 128 + j * 16 + l16;
      float u = acc[j][r] + q[row * 512 + col];
      uval[j][r] = u;
      s[r] += u;
      ss[r] = fmaf(u, u, ss[r]);
    }
  }
  #pragma unroll
  for (int o = 1; o <= 8; o <<= 1) {
    #pragma unroll
    for (int r = 0; r < 4; ++r) { s[r] += __shfl_xor(s[r], o); ss[r] += __shfl_xor(ss[r], o); }
  }
  if (l16 == 0) {
    #pragma unroll
    for (int r = 0; r < 4; ++r) {
      lnbuf[wave][quad * 4 + r][0] = s[r];
      lnbuf[wave][quad * 4 + r][1] = ss[r];
    }
  }
  __syncthreads();
  if (tid < 16) {
    float S = 0.f, SS = 0.f;
    #pragma unroll
    for (int w = 0; w < 4; ++w) { S += lnbuf[w][tid][0]; SS += lnbuf[w][tid][1]; }
    const float mu = S * (1.0f / 512.0f);
    const float var = SS * (1.0f / 512.0f) - mu * mu;
    lnmv[tid][0] = mu;
    lnmv[tid][1] = 1.0f / sqrtf(var + 1e-6f);
  }
  __syncthreads();
  #pragma unroll
  for (int r = 0; r < 4; ++r) {
    const int rr = quad * 4 + r;
    const float mu = lnmv[rr][0], inv = lnmv[rr][1];
    const long row = (long)b * 512 + m0 + rr;
    #pragma unroll
    for (int j = 0; j < 8; ++j) {
      const int col = wave * 128 + j * 16 + l16;
      outp[row * 512 + col] = (uval[j][r] - mu) * inv * gamma[col] + beta[col];
    }
  }
}

extern "C" void kernel_launch(void* const* d_in, const int* in_sizes, int n_in,
                              void* d_out, int out_size, void* d_ws, size_t ws_size,
                              hipStream_t stream) {
    const float* q     = (const float*)d_in[0];
    const float* k     = (const float*)d_in[1];
    const float* v     = (const float*)d_in[2];
    const float* x     = (const float*)d_in[3];
    const int*   lens  = (const int*)d_in[4];
    const float* Wq    = (const float*)d_in[5];
    const float* Wk    = (const float*)d_in[6];
    const float* Wv    = (const float*)d_in[7];
    const float* Wqf   = (const float*)d_in[8];
    const float* Wkf   = (const float*)d_in[9];
    const float* Wfc   = (const float*)d_in[10];
    const float* imp   = (const float*)d_in[11];
    const float* gamma = (const float*)d_in[12];
    const float* beta  = (const float*)d_in[13];

    constexpr long MB = 1 << 20;
    char* w = (char*)d_ws;
    __bf16* qfkfT = (__bf16*)(w);            //  0.. 8MB : qfT,kfT
    __bf16* vpb   = (__bf16*)(w + 8 * MB);   //  8..12MB : vp
    __bf16* vp2T  = (__bf16*)(w + 12 * MB);  // 12..16MB : vp2T
    __bf16* qcat  = (__bf16*)(w + 16 * MB);  // 16..24MB : [qp | qf2] K=1024
    __bf16* kcat  = (__bf16*)(w + 24 * MB);  // 24..32MB : [kp | kf2]
    __bf16* featb = (__bf16*)(w + 32 * MB);  // 32..36MB : feat_attn bf16
    __bf16* attnb = (__bf16*)(w + 36 * MB);  // 36..40MB : attn bf16

    float*  outp  = (float*)d_out;           // output 0 [B,L,D]
    float*  attnf = outp + NE;               // output 1 [B,L,L]

    // 1) 5 projections (128x128, fp32 in-reg cvt, XCD-swizzled) + feature softmax
    projfeat_kernel<<<dim3(768), 256, 0, stream>>>(q, k, v, Wq, Wk, Wqf, Wkf, Wv,
                                                   x, imp, lens,
                                                   qcat, kcat, qfkfT, vpb, featb);

    // 2) qf2,kf2 -> cat right halves + vp2T = Wfc.vp^T (384 blocks, 128x128)
    mega2_kernel<<<dim3(4, 4, 24), 256, 0, stream>>>(featb, qfkfT, Wfc, vpb,
                                                     qcat, kcat, vp2T);

    // 3) attn = tanh(mask(qcat.kcat^T / temp)), K=1024 (512 blocks, 64x64)
    scores_kernel<<<dim3(8, 8, 8), 256, 0, stream>>>(qcat, kcat, lens, attnf, attnb);

    // 4) out = LN(attn @ vp2 + q) fused (256 blocks, full-row)
    av2ln_kernel<<<dim3(32, 1, 8), 256, 0, stream>>>(attnb, vp2T, q, gamma, beta, outp);
}

// Round 13
// 179.160 us; speedup vs baseline: 1.1783x; 1.1783x over previous
//
#include <hip/hip_runtime.h>
#include <math.h>

typedef __bf16 bf16x8 __attribute__((ext_vector_type(8)));
typedef __bf16 bf16x4 __attribute__((ext_vector_type(4)));
typedef float  f32x4  __attribute__((ext_vector_type(4)));

namespace {
constexpr int L_ = 512, D_ = 512, NF = 11;
constexpr long WE = (long)L_ * L_;   // 262144 elems, one 512x512 plane
constexpr long NE = 8 * WE;          // 2097152 elems, B*L*D
constexpr long CPL = 512L * 1024;    // concatenated plane (512 rows x 1024)
constexpr float NEGV = -1.0e9f;
constexpr float INV_TEMP = 0.044194173824159216f; // 1/sqrt(512)
}

typedef __attribute__((address_space(1))) void gv_t;
typedef __attribute__((address_space(3))) void lv_t;

__device__ __forceinline__ void async_cp16(const void* g, void* l) {
  __builtin_amdgcn_global_load_lds((gv_t*)g, (lv_t*)l, 16, 0, 0);
}

__device__ __forceinline__ bf16x8 cvt2(float4 a0, float4 a1) {
  bf16x8 f;
  f[0] = (__bf16)a0.x; f[1] = (__bf16)a0.y; f[2] = (__bf16)a0.z; f[3] = (__bf16)a0.w;
  f[4] = (__bf16)a1.x; f[5] = (__bf16)a1.y; f[6] = (__bf16)a1.z; f[7] = (__bf16)a1.w;
  return f;
}

// ======== 128x128 NT core: 4 waves x (64x64, 4x4 acc), BK=64 as two 32-panels ========
// VGPR-prefetch staging with R5's scattered chunk map (bank-friendly):
// thread t stages chunks {row=srow(+64)} x {panel 0,1}, srow=t>>2, scol=(t&3)*8.
// fp32 operands converted in-register (same RNE points as a pre-conversion pass).
template<bool AF32, bool BF32>
__device__ __forceinline__ void core_big(const void* Av, const void* Bv,
                                         int K, int m0, int n0,
                                         __bf16* sA, __bf16* sB, f32x4 (&acc)[4][4])
{
  const int tid = threadIdx.x;
  const int wave = tid >> 6, lane = tid & 63;
  const int quad = lane >> 4, l16 = lane & 15;
  const int wm = (wave >> 1) * 64, wn = (wave & 1) * 64;
  const int srow = tid >> 2, scol = (tid & 3) * 8;
  const float*  gAf = (const float*)Av  + (long)(m0 + srow) * K + scol;
  const __bf16* gAb = (const __bf16*)Av + (long)(m0 + srow) * K + scol;
  const float*  gBf = (const float*)Bv  + (long)(n0 + srow) * K + scol;
  const __bf16* gBb = (const __bf16*)Bv + (long)(n0 + srow) * K + scol;
  // chunk c: global offset gofs[c], LDS offset dofs[c] (panels: [2][128][32])
  const long gofs[4] = {0, 32, (long)64 * K, (long)64 * K + 32};
  const int  dofs[4] = {0, 4096, 64 * 32, 4096 + 64 * 32};
  __bf16* dA = sA + srow * 32 + scol;
  __bf16* dB = sB + srow * 32 + scol;

  float4 fa[4][2], fb[4][2];
  bf16x8 ba[4], bb[4];

  // tile-0 prefetch
  #pragma unroll
  for (int c = 0; c < 4; ++c) {
    if (AF32) { fa[c][0] = *(const float4*)(gAf + gofs[c]); fa[c][1] = *(const float4*)(gAf + gofs[c] + 4); }
    else      { ba[c] = *(const bf16x8*)(gAb + gofs[c]); }
    if (BF32) { fb[c][0] = *(const float4*)(gBf + gofs[c]); fb[c][1] = *(const float4*)(gBf + gofs[c] + 4); }
    else      { bb[c] = *(const bf16x8*)(gBb + gofs[c]); }
  }

  for (int k0 = 0; k0 < K; k0 += 64) {
    __syncthreads();                 // all waves done reading previous LDS tile
    #pragma unroll
    for (int c = 0; c < 4; ++c) {
      bf16x8 wa = AF32 ? cvt2(fa[c][0], fa[c][1]) : ba[c];
      *(bf16x8*)(dA + dofs[c]) = wa;
      bf16x8 wb = BF32 ? cvt2(fb[c][0], fb[c][1]) : bb[c];
      *(bf16x8*)(dB + dofs[c]) = wb;
    }
    __syncthreads();                 // writes visible
    if (k0 + 64 < K) {               // issue next tile's loads; waits land next iter
      const int kn = k0 + 64;
      #pragma unroll
      for (int c = 0; c < 4; ++c) {
        if (AF32) { fa[c][0] = *(const float4*)(gAf + kn + gofs[c]); fa[c][1] = *(const float4*)(gAf + kn + gofs[c] + 4); }
        else      { ba[c] = *(const bf16x8*)(gAb + kn + gofs[c]); }
        if (BF32) { fb[c][0] = *(const float4*)(gBf + kn + gofs[c]); fb[c][1] = *(const float4*)(gBf + kn + gofs[c] + 4); }
        else      { bb[c] = *(const bf16x8*)(gBb + kn + gofs[c]); }
      }
    }
    #pragma unroll
    for (int p = 0; p < 2; ++p) {
      bf16x8 af[4], bfr[4];
      #pragma unroll
      for (int i = 0; i < 4; ++i)
        af[i]  = *(const bf16x8*)(sA + p * 4096 + (wm + i * 16 + l16) * 32 + quad * 8);
      #pragma unroll
      for (int j = 0; j < 4; ++j)
        bfr[j] = *(const bf16x8*)(sB + p * 4096 + (wn + j * 16 + l16) * 32 + quad * 8);
      #pragma unroll
      for (int i = 0; i < 4; ++i)
        #pragma unroll
        for (int j = 0; j < 4; ++j)
          acc[i][j] = __builtin_amdgcn_mfma_f32_16x16x32_bf16(af[i], bfr[j], acc[i][j], 0, 0, 0);
    }
  }
}

// ======== 64x64 NT core, BK=64 panels, bf16 operands (scores) ========
__device__ __forceinline__ void core64(const __bf16* __restrict__ A, const __bf16* __restrict__ B,
                                       int K, int m0, int n0,
                                       __bf16* sA, __bf16* sB, f32x4 (&acc)[2][2])
{
  const int tid = threadIdx.x;
  const int wave = tid >> 6, lane = tid & 63;
  const int srow = tid >> 2, scol = (tid & 3) * 8;
  const int quad = lane >> 4, l16 = lane & 15;
  const int wm = (wave >> 1) * 32, wn = (wave & 1) * 32;
  const __bf16* gA = A + (long)(m0 + srow) * K + scol;
  const __bf16* gB = B + (long)(n0 + srow) * K + scol;
  __bf16* dA = sA + srow * 32 + scol;
  __bf16* dB = sB + srow * 32 + scol;

  bf16x8 ra[2], rb[2];
  ra[0] = *(const bf16x8*)(gA);
  ra[1] = *(const bf16x8*)(gA + 32);
  rb[0] = *(const bf16x8*)(gB);
  rb[1] = *(const bf16x8*)(gB + 32);

  for (int k0 = 0; k0 < K; k0 += 64) {
    __syncthreads();
    *(bf16x8*)(dA)        = ra[0];
    *(bf16x8*)(dA + 2048) = ra[1];
    *(bf16x8*)(dB)        = rb[0];
    *(bf16x8*)(dB + 2048) = rb[1];
    __syncthreads();
    if (k0 + 64 < K) {
      const int kn = k0 + 64;
      ra[0] = *(const bf16x8*)(gA + kn);
      ra[1] = *(const bf16x8*)(gA + kn + 32);
      rb[0] = *(const bf16x8*)(gB + kn);
      rb[1] = *(const bf16x8*)(gB + kn + 32);
    }
    #pragma unroll
    for (int p = 0; p < 2; ++p) {
      bf16x8 af[2], bfr[2];
      #pragma unroll
      for (int i = 0; i < 2; ++i)
        af[i]  = *(const bf16x8*)(sA + p * 2048 + (wm + i * 16 + l16) * 32 + quad * 8);
      #pragma unroll
      for (int j = 0; j < 2; ++j)
        bfr[j] = *(const bf16x8*)(sB + p * 2048 + (wn + j * 16 + l16) * 32 + quad * 8);
      #pragma unroll
      for (int i = 0; i < 2; ++i)
        #pragma unroll
        for (int j = 0; j < 2; ++j)
          acc[i][j] = __builtin_amdgcn_mfma_f32_16x16x32_bf16(af[i], bfr[j], acc[i][j], 0, 0, 0);
    }
  }
}

// ======== projfeat: flat grid. fid<640: 128x128 GEMM (XCD-swizzled); fid>=640: feat ========
// z: 0=qp->qcat[:,:512] 1=kp->kcat[:,:512] 2=qfT 3=kfT 4=vp
__global__ __launch_bounds__(256)
void projfeat_kernel(const float* __restrict__ q, const float* __restrict__ k,
                     const float* __restrict__ v,
                     const float* __restrict__ Wq, const float* __restrict__ Wk,
                     const float* __restrict__ Wqf, const float* __restrict__ Wkf,
                     const float* __restrict__ Wv,
                     const float* __restrict__ x, const float* __restrict__ imp,
                     const int* __restrict__ lens,
                     __bf16* __restrict__ qcat, __bf16* __restrict__ kcat,
                     __bf16* __restrict__ qfkfT, __bf16* __restrict__ vpb,
                     __bf16* __restrict__ featb)
{
  __shared__ __align__(16) char smem[32768]; // GEMM: sA 16K + sB 16K; feat: 22.5K
  const int fid = blockIdx.x;
  const int tid = threadIdx.x;
  const int wave = tid >> 6, lane = tid & 63;

  if (fid < 640) {
    const int xcd = fid & 7, g = fid >> 3;       // g in [0,80)
    const int n = g & 3, mh = (g >> 2) & 3, z = g >> 4;
    const int m0 = (mh * 8 + xcd) * 128;         // m-tile in [0,32)
    const int n0 = n * 128;
    __bf16* sA = (__bf16*)smem;
    __bf16* sB = sA + 2 * 128 * 32;
    const float* As[5] = {q, k, q, k, v};
    const float* Bs[5] = {Wq, Wk, Wqf, Wkf, Wv};
    f32x4 acc[4][4];
    #pragma unroll
    for (int i = 0; i < 4; ++i)
      #pragma unroll
      for (int j = 0; j < 4; ++j) acc[i][j] = 0.0f;
    core_big<true, true>(As[z], Bs[z], 512, m0, n0, sA, sB, acc);

    const int quad = lane >> 4, l16 = lane & 15;
    const int wm = (wave >> 1) * 64, wn = (wave & 1) * 64;
    #pragma unroll
    for (int i = 0; i < 4; ++i) {
      const int mb = m0 + wm + i * 16 + quad * 4;
      #pragma unroll
      for (int j = 0; j < 4; ++j) {
        const int nn = n0 + wn + j * 16 + l16;
        f32x4 c = acc[i][j];
        if (z < 2) {
          __bf16* C = (z == 0) ? qcat : kcat;
          #pragma unroll
          for (int r2 = 0; r2 < 4; ++r2)
            C[(long)(mb + r2) * 1024 + nn] = (__bf16)c[r2];
        } else if (z == 4) {
          #pragma unroll
          for (int r2 = 0; r2 < 4; ++r2)
            vpb[(long)(mb + r2) * 512 + nn] = (__bf16)c[r2];
        } else {
          __bf16* T = qfkfT + (long)(z - 2) * NE;
          const long bb = (long)(mb >> 9) << 18;
          const int l = mb & 511;
          bf16x4 pk;
          pk[0] = (__bf16)c[0]; pk[1] = (__bf16)c[1];
          pk[2] = (__bf16)c[2]; pk[3] = (__bf16)c[3];
          *(bf16x4*)(T + bb + (long)nn * 512 + l) = pk;
        }
      }
    }
  } else {
    const int flat = fid - 640;                  // 0..127
    float* xfs = (float*)smem;                   // 22.5 KB
    const int b = flat >> 4;
    const int i0 = (flat & 15) * 32;
    for (int idx = tid; idx < L_ * NF; idx += 256) {
      int j = idx / NF, f = idx - j * NF;
      xfs[idx] = x[((long)b * L_ + j) * D_ + f];
    }
    float im[NF];
    #pragma unroll
    for (int f = 0; f < NF; ++f) im[f] = imp[f];
    const int len = lens[b];
    __syncthreads();
    for (int r = 0; r < 8; ++r) {
      const int i = i0 + wave * 8 + r;
      float xi[NF];
      #pragma unroll
      for (int f = 0; f < NF; ++f) xi[f] = xfs[i * NF + f];
      float l[8];
      float m = -INFINITY;
      #pragma unroll
      for (int t = 0; t < 8; ++t) {
        int j = lane + t * 64;
        float s = 0.f;
        #pragma unroll
        for (int f = 0; f < NF; ++f) s = fmaf(fabsf(xi[f] - xfs[j * NF + f]), im[f], s);
        s = (j < len) ? s : NEGV;
        l[t] = s;
        m = fmaxf(m, s);
      }
      #pragma unroll
      for (int o = 32; o >= 1; o >>= 1) m = fmaxf(m, __shfl_xor(m, o));
      float ssum = 0.f;
      #pragma unroll
      for (int t = 0; t < 8; ++t) { l[t] = expf(l[t] - m); ssum += l[t]; }
      #pragma unroll
      for (int o = 32; o >= 1; o >>= 1) ssum += __shfl_xor(ssum, o);
      float inv = 1.0f / ssum;
      #pragma unroll
      for (int t = 0; t < 8; ++t)
        featb[((long)b * L_ + i) * L_ + lane + t * 64] = (__bf16)(l[t] * inv);
    }
  }
}

// mega2 (128x128 core): z 0..7 qf2->qcat[:,512:], 8..15 kf2->kcat[:,512:], 16..23 vp2T=NT(Wfc,vp[b])
__global__ __launch_bounds__(256)
void mega2_kernel(const __bf16* __restrict__ featb, const __bf16* __restrict__ qfkfT,
                  const float* __restrict__ Wfc, const __bf16* __restrict__ vpb,
                  __bf16* __restrict__ qcat, __bf16* __restrict__ kcat,
                  __bf16* __restrict__ vp2T)
{
  __shared__ __align__(16) __bf16 sA[2 * 128 * 32];
  __shared__ __align__(16) __bf16 sB[2 * 128 * 32];
  const int z = blockIdx.z;
  const int m0 = blockIdx.y * 128, n0 = blockIdx.x * 128;
  f32x4 acc[4][4];
  #pragma unroll
  for (int i = 0; i < 4; ++i)
    #pragma unroll
    for (int j = 0; j < 4; ++j) acc[i][j] = 0.0f;

  __bf16* C;
  int ldc;
  if (z < 16) {
    const int b = z & 7, s = z >> 3;
    const __bf16* A = featb + (long)b * WE;
    const __bf16* B = qfkfT + (long)s * NE + (long)b * WE;
    C = (s ? kcat : qcat) + (long)b * CPL + 512;
    ldc = 1024;
    core_big<false, false>(A, B, 512, m0, n0, sA, sB, acc);
  } else {
    const int b = z - 16;
    const __bf16* B = vpb + (long)b * WE;
    C = vp2T + (long)b * WE;
    ldc = 512;
    core_big<true, false>(Wfc, B, 512, m0, n0, sA, sB, acc);
  }

  const int wave = threadIdx.x >> 6, lane = threadIdx.x & 63;
  const int quad = lane >> 4, l16 = lane & 15;
  const int wm = (wave >> 1) * 64, wn = (wave & 1) * 64;
  #pragma unroll
  for (int i = 0; i < 4; ++i) {
    const int mb = m0 + wm + i * 16 + quad * 4;
    #pragma unroll
    for (int j = 0; j < 4; ++j) {
      const int nn = n0 + wn + j * 16 + l16;
      f32x4 c = acc[i][j];
      #pragma unroll
      for (int r2 = 0; r2 < 4; ++r2)
        C[(long)(mb + r2) * ldc + nn] = (__bf16)c[r2];
    }
  }
}

// scores: attn = tanh(mask(./temp)), K=1024, 64x64 tiles; writes fp32 (out1) + bf16 (for av2)
__global__ __launch_bounds__(256)
void scores_kernel(const __bf16* __restrict__ qcat, const __bf16* __restrict__ kcat,
                   const int* __restrict__ lens, float* __restrict__ attnf,
                   __bf16* __restrict__ attnb)
{
  __shared__ __align__(16) __bf16 sA[2 * 64 * 32];
  __shared__ __align__(16) __bf16 sB[2 * 64 * 32];
  const int b = blockIdx.z;
  const int len = lens[b];
  const int m0 = blockIdx.y * 64, n0 = blockIdx.x * 64;
  f32x4 acc[2][2];
  #pragma unroll
  for (int i = 0; i < 2; ++i)
    #pragma unroll
    for (int j = 0; j < 2; ++j) acc[i][j] = 0.0f;
  core64(qcat + (long)b * CPL, kcat + (long)b * CPL, 1024, m0, n0, sA, sB, acc);

  const long off = (long)b * WE;
  const int wave = threadIdx.x >> 6, lane = threadIdx.x & 63;
  const int quad = lane >> 4, l16 = lane & 15;
  const int wm = (wave >> 1) * 32, wn = (wave & 1) * 32;
  #pragma unroll
  for (int i = 0; i < 2; ++i) {
    const int mb = m0 + wm + i * 16 + quad * 4;
    #pragma unroll
    for (int j = 0; j < 2; ++j) {
      const int nn = n0 + wn + j * 16 + l16;
      f32x4 c = acc[i][j];
      #pragma unroll
      for (int r2 = 0; r2 < 4; ++r2) {
        float vv = c[r2] * INV_TEMP;
        vv = (nn < len) ? tanhf(vv) : 0.0f;
        attnf[off + (long)(mb + r2) * 512 + nn] = vv;
        attnb[off + (long)(mb + r2) * 512 + nn] = (__bf16)vv;
      }
    }
  }
}

// ======== av2ln: out = LN(attn@vp2 + q); block = 16 rows x full 512 cols ========
__global__ __launch_bounds__(256)
void av2ln_kernel(const __bf16* __restrict__ attnb, const __bf16* __restrict__ vp2T,
                  const float* __restrict__ q, const float* __restrict__ gamma,
                  const float* __restrict__ beta, float* __restrict__ outp)
{
  __shared__ __align__(16) __bf16 sA[16 * 32];     // 1 KB
  __shared__ __align__(16) __bf16 sB[512 * 32];    // 32 KB
  __shared__ float lnbuf[4][16][2];
  __shared__ float lnmv[16][2];
  const int b = blockIdx.z;
  const int m0 = blockIdx.x * 16;
  const int tid = threadIdx.x;
  const int wave = tid >> 6, lane = tid & 63;
  const int quad = lane >> 4, l16 = lane & 15;
  const long aoff = (long)b * WE;

  f32x4 acc[8];
  #pragma unroll
  for (int j = 0; j < 8; ++j) acc[j] = 0.0f;

  for (int k0 = 0; k0 < 512; k0 += 32) {
    __syncthreads();
    if (wave == 0) {
      const int ar = lane >> 2, ac = (lane & 3) * 8;
      async_cp16(attnb + aoff + (long)(m0 + ar) * 512 + k0 + ac, (char*)sA + lane * 16);
    }
    #pragma unroll
    for (int it = 0; it < 8; ++it) {
      const int chunk = it * 4 + wave;
      const int d = chunk * 16 + (lane >> 2), c = (lane & 3) * 8;
      async_cp16(vp2T + aoff + (long)d * 512 + k0 + c, (char*)sB + chunk * 1024 + lane * 16);
    }
    __syncthreads();
    bf16x8 af = *(const bf16x8*)(sA + l16 * 32 + quad * 8);
    #pragma unroll
    for (int j = 0; j < 8; ++j) {
      bf16x8 bfr = *(const bf16x8*)(sB + (wave * 128 + j * 16 + l16) * 32 + quad * 8);
      acc[j] = __builtin_amdgcn_mfma_f32_16x16x32_bf16(af, bfr, acc[j], 0, 0, 0);
    }
  }

  float uval[8][4];
  float s[4] = {0.f, 0.f, 0.f, 0.f}, ss[4] = {0.f, 0.f, 0.f, 0.f};
  #pragma unroll
  for (int r = 0; r < 4; ++r) {
    const long row = (long)b * 512 + m0 + quad * 4 + r;
    #pragma unroll
    for (int j = 0; j < 8; ++j) {
      const int col = wave * 128 + j * 16 + l16;
      float u = acc[j][r] + q[row * 512 + col];
      uval[j][r] = u;
      s[r] += u;
      ss[r] = fmaf(u, u, ss[r]);
    }
  }
  #pragma unroll
  for (int o = 1; o <= 8; o <<= 1) {
    #pragma unroll
    for (int r = 0; r < 4; ++r) { s[r] += __shfl_xor(s[r], o); ss[r] += __shfl_xor(ss[r], o); }
  }
  if (l16 == 0) {
    #pragma unroll
    for (int r = 0; r < 4; ++r) {
      lnbuf[wave][quad * 4 + r][0] = s[r];
      lnbuf[wave][quad * 4 + r][1] = ss[r];
    }
  }
  __syncthreads();
  if (tid < 16) {
    float S = 0.f, SS = 0.f;
    #pragma unroll
    for (int w = 0; w < 4; ++w) { S += lnbuf[w][tid][0]; SS += lnbuf[w][tid][1]; }
    const float mu = S * (1.0f / 512.0f);
    const float var = SS * (1.0f / 512.0f) - mu * mu;
    lnmv[tid][0] = mu;
    lnmv[tid][1] = 1.0f / sqrtf(var + 1e-6f);
  }
  __syncthreads();
  #pragma unroll
  for (int r = 0; r < 4; ++r) {
    const int rr = quad * 4 + r;
    const float mu = lnmv[rr][0], inv = lnmv[rr][1];
    const long row = (long)b * 512 + m0 + rr;
    #pragma unroll
    for (int j = 0; j < 8; ++j) {
      const int col = wave * 128 + j * 16 + l16;
      outp[row * 512 + col] = (uval[j][r] - mu) * inv * gamma[col] + beta[col];
    }
  }
}

extern "C" void kernel_launch(void* const* d_in, const int* in_sizes, int n_in,
                              void* d_out, int out_size, void* d_ws, size_t ws_size,
                              hipStream_t stream) {
    const float* q     = (const float*)d_in[0];
    const float* k     = (const float*)d_in[1];
    const float* v     = (const float*)d_in[2];
    const float* x     = (const float*)d_in[3];
    const int*   lens  = (const int*)d_in[4];
    const float* Wq    = (const float*)d_in[5];
    const float* Wk    = (const float*)d_in[6];
    const float* Wv    = (const float*)d_in[7];
    const float* Wqf   = (const float*)d_in[8];
    const float* Wkf   = (const float*)d_in[9];
    const float* Wfc   = (const float*)d_in[10];
    const float* imp   = (const float*)d_in[11];
    const float* gamma = (const float*)d_in[12];
    const float* beta  = (const float*)d_in[13];

    constexpr long MB = 1 << 20;
    char* w = (char*)d_ws;
    __bf16* qfkfT = (__bf16*)(w);            //  0.. 8MB : qfT,kfT
    __bf16* vpb   = (__bf16*)(w + 8 * MB);   //  8..12MB : vp
    __bf16* vp2T  = (__bf16*)(w + 12 * MB);  // 12..16MB : vp2T
    __bf16* qcat  = (__bf16*)(w + 16 * MB);  // 16..24MB : [qp | qf2] K=1024
    __bf16* kcat  = (__bf16*)(w + 24 * MB);  // 24..32MB : [kp | kf2]
    __bf16* featb = (__bf16*)(w + 32 * MB);  // 32..36MB : feat_attn bf16
    __bf16* attnb = (__bf16*)(w + 36 * MB);  // 36..40MB : attn bf16

    float*  outp  = (float*)d_out;           // output 0 [B,L,D]
    float*  attnf = outp + NE;               // output 1 [B,L,L]

    // 1) 5 projections (128x128, fp32 in-reg cvt, XCD-swizzled) + feature softmax
    projfeat_kernel<<<dim3(768), 256, 0, stream>>>(q, k, v, Wq, Wk, Wqf, Wkf, Wv,
                                                   x, imp, lens,
                                                   qcat, kcat, qfkfT, vpb, featb);

    // 2) qf2,kf2 -> cat right halves + vp2T = Wfc.vp^T (384 blocks, 128x128)
    mega2_kernel<<<dim3(4, 4, 24), 256, 0, stream>>>(featb, qfkfT, Wfc, vpb,
                                                     qcat, kcat, vp2T);

    // 3) attn = tanh(mask(qcat.kcat^T / temp)), K=1024 (512 blocks, 64x64)
    scores_kernel<<<dim3(8, 8, 8), 256, 0, stream>>>(qcat, kcat, lens, attnf, attnb);

    // 4) out = LN(attn @ vp2 + q) fused (256 blocks, full-row)
    av2ln_kernel<<<dim3(32, 1, 8), 256, 0, stream>>>(attnb, vp2T, q, gamma, beta, outp);
}